// Round 18
// baseline (136.187 us; speedup 1.0000x reference)
//
#include <hip/hip_runtime.h>

#define B_   32
#define H_   16
#define L_   577
#define D_   1024
#define CK   64
#define LP   576    // L-1 patches = 9*64 exactly
#define DOM  54
#define NSEL 55     // DOM + CLS
#define NR   522    // LP - DOM
#define CTX  10
#define NMERGE 512  // NR - CTX
#define BL   (B_ * LP)

#define NPRE_BLK 1224           // 72 Sd + 1152 cos
#define NA_BLK   (NPRE_BLK + 288)
#define NASG_BLK 256            // 8 per batch
#define NHVY_BLK (B_ * CTX)     // 320
#define NCPY_BLK (B_ * NSEL)    // 1760
#define NB_BLK   (NASG_BLK + NHVY_BLK + NCPY_BLK)

// remain-list position for merge index m: p = m + min(m/51,9) + 1
__device__ __forceinline__ int remain_pos(int m) {
    int k = m / 51; if (k > 9) k = 9;
    return m + k + 1;
}

__device__ __forceinline__ int nth_set_bit64(unsigned long long x, int r) {
    int pos = 0;
    #pragma unroll
    for (int sh = 32; sh >= 1; sh >>= 1) {
        int c = __popcll(x & ((1ull << sh) - 1));
        if (r >= c) { r -= c; x >>= sh; pos += sh; }
    }
    return pos;
}
__device__ int nth_zero_576(const unsigned long long* w, int r) {
    #pragma unroll
    for (int i = 0; i < 9; ++i) {
        int c = 64 - __popcll(w[i]);
        if (r < c) return i * 64 + nth_set_bit64(~w[i], r);
        r -= c;
    }
    return 0;
}
__device__ int nth_set_576(const unsigned long long* w, int r) {
    #pragma unroll
    for (int i = 0; i < 9; ++i) {
        int c = __popcll(w[i]);
        if (r < c) return i * 64 + nth_set_bit64(w[i], r);
        r -= c;
    }
    return 0;
}

// producer epilogue: barrier then thread-0 release-increment
__device__ __forceinline__ void signal_done(unsigned int* cnt) {
    __syncthreads();
    if (threadIdx.x == 0)
        __hip_atomic_fetch_add(cnt, 1u, __ATOMIC_RELEASE, __HIP_MEMORY_SCOPE_AGENT);
}
// consumer prologue: thread-0 acquire-spin then barrier
__device__ __forceinline__ void wait_for(unsigned int* cnt, unsigned int tgt) {
    if (threadIdx.x == 0) {
        while (__hip_atomic_load(cnt, __ATOMIC_ACQUIRE, __HIP_MEMORY_SCOPE_AGENT) < tgt)
            __builtin_amdgcn_s_sleep(8);
    }
    __syncthreads();
}

// ===== K_A: pre (Sd partials + cos) producers, rank consumers =====
__global__ __launch_bounds__(256) void k_a(
    const float* __restrict__ attn, const float* __restrict__ metric,
    const float* __restrict__ text, unsigned int* __restrict__ cnt,
    float* __restrict__ Sd_part, float* __restrict__ cos_arr,
    unsigned long long* __restrict__ selbits)
{
    const int bid = blockIdx.x, tid = threadIdx.x;
    if (bid < 72) {
        // Sd partials (R17): thread sums 4 heads over 4 js (float4)
        int i = bid * 256 + tid;
        int q4 = i / 4608, r = i - q4 * 4608;     // 4608 = B_ * 144
        int b = r / 144, j4 = r - b * 144;
        const size_t LL = (size_t)L_ * L_;
        size_t base = ((size_t)b * H_ + 4 * q4) * LL + 1 + 4 * j4;
        float4 s0 = *(const float4*)&attn[base];
        float4 s1 = *(const float4*)&attn[base + LL];
        float4 s2 = *(const float4*)&attn[base + 2 * LL];
        float4 s3 = *(const float4*)&attn[base + 3 * LL];
        float4 s;
        s.x = (s0.x + s1.x) + (s2.x + s3.x);
        s.y = (s0.y + s1.y) + (s2.y + s3.y);
        s.z = (s0.z + s1.z) + (s2.z + s3.z);
        s.w = (s0.w + s1.w) + (s2.w + s3.w);
        *(float4*)&Sd_part[q4 * BL + b * LP + 4 * j4] = s;
        signal_done(&cnt[0]);
    } else if (bid < NPRE_BLK) {
        // cos (R17): one batch per block, 16 rows, 16-lane groups
        const int cb = bid - 72;
        const int b = cb / 36, row0 = (cb % 36) * 16;
        const int wv = tid >> 6, lane = tid & 63;
        const int g = lane >> 4, q = lane & 15;
        __shared__ float tsh[CK];
        __shared__ float invtn_sh;

        if (tid < CK) {
            float t = text[b * CK + tid];
            tsh[tid] = t;
            float s2 = t * t;
            for (int o = 32; o; o >>= 1) s2 += __shfl_xor(s2, o);
            if (tid == 0) invtn_sh = 1.f / (sqrtf(s2) + 1e-12f);
        }
        __syncthreads();

        const int j = row0 + wv * 4 + g;
        float4 mv = *(const float4*)&metric[((size_t)(b * L_ + 1 + j)) * CK + 4 * q];
        float4 tv = *(const float4*)&tsh[4 * q];
        float d  = mv.x * tv.x + mv.y * tv.y + mv.z * tv.z + mv.w * tv.w;
        float ss = mv.x * mv.x + mv.y * mv.y + mv.z * mv.z + mv.w * mv.w;
        #pragma unroll
        for (int o = 1; o < 16; o <<= 1) {
            d += __shfl_xor(d, o); ss += __shfl_xor(ss, o);
        }
        if (q == 0)
            cos_arr[b * LP + j] = d / (sqrtf(ss) + 1e-12f) * invtn_sh;
        signal_done(&cnt[0]);
    } else {
        // rank (R17 body) — waits for all 1224 pre blocks
        wait_for(&cnt[0], NPRE_BLK);
        const int rb = bid - NPRE_BLK;
        const int b = rb / 9, slice = rb % 9;
        const int wv = tid >> 6, lane = tid & 63;

        __shared__ float sdv[LP];
        __shared__ float csv[LP];
        __shared__ float red[8];
        __shared__ int   prank[256];

        float sumS = 0.f, sumC = 0.f;
        for (int j = tid; j < LP; j += 256) {
            const int idx = b * LP + j;
            float Sd = (Sd_part[idx] + Sd_part[BL + idx]) +
                       (Sd_part[2 * BL + idx] + Sd_part[3 * BL + idx]);
            float cs = cos_arr[idx];
            sdv[j] = Sd; csv[j] = cs;
            sumS += Sd; sumC += cs;
        }
        {
            float a = sumS, c2 = sumC;
            for (int o = 32; o; o >>= 1) { a += __shfl_xor(a, o); c2 += __shfl_xor(c2, o); }
            if (lane == 0) { red[wv] = a; red[4 + wv] = c2; }
        }
        __syncthreads();
        const float mS = ((red[0] + red[1]) + (red[2] + red[3])) * (1.f / LP);
        const float mC = ((red[4] + red[5]) + (red[6] + red[7])) * (1.f / LP);
        __syncthreads();

        float s2S = 0.f, s2C = 0.f;
        for (int j = tid; j < LP; j += 256) {
            float dS = sdv[j] - mS, dC = csv[j] - mC;
            s2S += dS * dS; s2C += dC * dC;
        }
        {
            float a = s2S, c2 = s2C;
            for (int o = 32; o; o >>= 1) { a += __shfl_xor(a, o); c2 += __shfl_xor(c2, o); }
            if (lane == 0) { red[wv] = a; red[4 + wv] = c2; }
        }
        __syncthreads();
        const float vS = ((red[0] + red[1]) + (red[2] + red[3])) * (1.f / (LP - 1));
        const float vC = ((red[4] + red[5]) + (red[6] + red[7])) * (1.f / (LP - 1));
        const float izS = 0.5f / (sqrtf(vS) + 1e-6f);
        const float izC = 0.5f / (sqrtf(vC) + 1e-6f);
        __syncthreads();

        for (int j = tid; j < LP; j += 256)
            sdv[j] = (sdv[j] - mS) * izS + (csv[j] - mC) * izC;
        __syncthreads();

        {
            const int j = slice * 64 + lane;
            const float my = sdv[j];
            int rk = 0;
            const int k0 = 144 * wv;
            for (int k = k0; k < k0 + 144; ++k) {
                float s = sdv[k];
                rk += (s > my) || (s == my && k < j);   // stable tie-break
            }
            prank[tid] = rk;
        }
        __syncthreads();
        if (tid < 64) {
            int tot = (prank[tid] + prank[tid + 64]) + (prank[tid + 128] + prank[tid + 192]);
            unsigned long long bm = __ballot(tot < DOM);
            if (tid == 0) selbits[b * 9 + slice] = bm;
        }
    }
}

// ===== K_B: assign producers, heavy consumers (per-batch), copies =====
__global__ __launch_bounds__(256) void k_b(
    const float* __restrict__ metric, const float* __restrict__ hidden,
    const unsigned long long* __restrict__ selbits,
    unsigned int* __restrict__ cnt, int* __restrict__ assign_tok,
    float* __restrict__ out)
{
    const int bid = blockIdx.x, tid = threadIdx.x;

    if (bid < NASG_BLK) {
        // ---- assignment: 4 lanes/token, 64 tokens/block ----
        const int b = bid >> 3, sub = bid & 7;
        const int wv = tid >> 6, lane = tid & 63;
        __shared__ int   t10[CTX];
        __shared__ float tg[CTX * CK];
        __shared__ float tinv[CTX];

        unsigned long long w[9];
        #pragma unroll
        for (int i = 0; i < 9; ++i) w[i] = selbits[b * 9 + i];

        if (tid < CTX) t10[tid] = nth_zero_576(w, 52 * tid) + 1;
        __syncthreads();
        for (int i = tid; i < CTX * CK; i += 256)
            tg[i] = metric[((size_t)(b * L_ + t10[i >> 6])) * CK + (i & 63)];
        __syncthreads();
        for (int k = wv; k < CTX; k += 4) {
            float t = tg[k * CK + lane];
            float s2 = t * t;
            for (int o = 32; o; o >>= 1) s2 += __shfl_xor(s2, o);
            if (lane == 0) tinv[k] = 1.f / (sqrtf(s2) + 1e-12f);
        }
        __syncthreads();

        const int m = sub * 64 + (tid >> 2);      // token index
        const int e = tid & 3;                     // component-quarter
        const int tok = nth_zero_576(w, remain_pos(m)) + 1;
        const float4* row = (const float4*)&metric[((size_t)(b * L_ + tok)) * CK + 16 * e];
        float4 r0 = row[0], r1 = row[1], r2 = row[2], r3 = row[3];

        // merge-row norm dropped: positive scalar, argmax-invariant
        float best = -1e30f; int bk = 0;
        #pragma unroll
        for (int k = 0; k < CTX; ++k) {
            const float4* tp = (const float4*)&tg[k * CK + 16 * e];
            float4 t0 = tp[0], t1 = tp[1], t2 = tp[2], t3 = tp[3];
            float d = ((r0.x*t0.x + r0.y*t0.y + r0.z*t0.z + r0.w*t0.w) +
                       (r1.x*t1.x + r1.y*t1.y + r1.z*t1.z + r1.w*t1.w)) +
                      ((r2.x*t2.x + r2.y*t2.y + r2.z*t2.z + r2.w*t2.w) +
                       (r3.x*t3.x + r3.y*t3.y + r3.z*t3.z + r3.w*t3.w));
            d += __shfl_xor(d, 1); d += __shfl_xor(d, 2);
            d *= tinv[k];
            if (d > best) { best = d; bk = k; }   // strict >: first max (jnp.argmax)
        }
        if (e == 0) assign_tok[b * NMERGE + m] = (tok << 4) | bk;
        signal_done(&cnt[1 + b]);
    } else if (bid < NASG_BLK + NHVY_BLK) {
        // ---- heavy contextual aggregate — waits on its batch's 8 assigns ----
        const int hb = bid - NASG_BLK;
        const int b = hb / CTX, k = hb % CTX;
        wait_for(&cnt[1 + b], 8);

        const int w = tid >> 6, lane = tid & 63;
        __shared__ int at[NMERGE];
        __shared__ int toks[NMERGE];
        __shared__ unsigned long long cmask[2][4];

        at[tid]       = assign_tok[b * NMERGE + tid];
        at[tid + 256] = assign_tok[b * NMERGE + tid + 256];
        __syncthreads();
        int a0 = at[tid], a1 = at[tid + 256];
        bool m0 = (a0 & 15) == k, m1 = (a1 & 15) == k;
        unsigned long long bl0 = __ballot(m0), bl1 = __ballot(m1);
        if (lane == 0) { cmask[0][w] = bl0; cmask[1][w] = bl1; }
        __syncthreads();
        int sum0 = 0, pre0 = 0, pre1 = 0;
        #pragma unroll
        for (int ww = 0; ww < 4; ++ww) {
            int p0 = __popcll(cmask[0][ww]);
            sum0 += p0;
            if (ww < w) { pre0 += p0; pre1 += __popcll(cmask[1][ww]); }
        }
        int sum1 = 0;
        #pragma unroll
        for (int ww = 0; ww < 4; ++ww) sum1 += __popcll(cmask[1][ww]);
        unsigned long long lt = (1ull << lane) - 1ull;
        if (m0) toks[pre0 + __popcll(bl0 & lt)] = a0 >> 4;
        if (m1) toks[sum0 + pre1 + __popcll(bl1 & lt)] = a1 >> 4;
        const int cnt2 = sum0 + sum1;
        __syncthreads();

        const float4* hb4 = (const float4*)&hidden[((size_t)b * L_) * D_];
        float4 a_0 = make_float4(0,0,0,0), a_1 = a_0, a_2 = a_0, a_3 = a_0;
        float4 a_4 = a_0, a_5 = a_0, a_6 = a_0, a_7 = a_0;
        int i = 0;
        for (; i + 8 <= cnt2; i += 8) {
            float4 v0 = hb4[(size_t)toks[i+0] * 256 + tid];
            float4 v1 = hb4[(size_t)toks[i+1] * 256 + tid];
            float4 v2 = hb4[(size_t)toks[i+2] * 256 + tid];
            float4 v3 = hb4[(size_t)toks[i+3] * 256 + tid];
            float4 v4 = hb4[(size_t)toks[i+4] * 256 + tid];
            float4 v5 = hb4[(size_t)toks[i+5] * 256 + tid];
            float4 v6 = hb4[(size_t)toks[i+6] * 256 + tid];
            float4 v7 = hb4[(size_t)toks[i+7] * 256 + tid];
            a_0.x += v0.x; a_0.y += v0.y; a_0.z += v0.z; a_0.w += v0.w;
            a_1.x += v1.x; a_1.y += v1.y; a_1.z += v1.z; a_1.w += v1.w;
            a_2.x += v2.x; a_2.y += v2.y; a_2.z += v2.z; a_2.w += v2.w;
            a_3.x += v3.x; a_3.y += v3.y; a_3.z += v3.z; a_3.w += v3.w;
            a_4.x += v4.x; a_4.y += v4.y; a_4.z += v4.z; a_4.w += v4.w;
            a_5.x += v5.x; a_5.y += v5.y; a_5.z += v5.z; a_5.w += v5.w;
            a_6.x += v6.x; a_6.y += v6.y; a_6.z += v6.z; a_6.w += v6.w;
            a_7.x += v7.x; a_7.y += v7.y; a_7.z += v7.z; a_7.w += v7.w;
        }
        for (; i < cnt2; ++i) {
            float4 v = hb4[(size_t)toks[i] * 256 + tid];
            a_0.x += v.x; a_0.y += v.y; a_0.z += v.z; a_0.w += v.w;
        }
        float4 acc;
        acc.x = ((a_0.x + a_1.x) + (a_2.x + a_3.x)) + ((a_4.x + a_5.x) + (a_6.x + a_7.x));
        acc.y = ((a_0.y + a_1.y) + (a_2.y + a_3.y)) + ((a_4.y + a_5.y) + (a_6.y + a_7.y));
        acc.z = ((a_0.z + a_1.z) + (a_2.z + a_3.z)) + ((a_4.z + a_5.z) + (a_6.z + a_7.z));
        acc.w = ((a_0.w + a_1.w) + (a_2.w + a_3.w)) + ((a_4.w + a_5.w) + (a_6.w + a_7.w));

        unsigned long long wsel[9];
        #pragma unroll
        for (int ii = 0; ii < 9; ++ii) wsel[ii] = selbits[b * 9 + ii];
        const int tgt_tok = nth_zero_576(wsel, 52 * k) + 1;
        float4 bv = hb4[(size_t)tgt_tok * 256 + tid];
        float inv = 1.0f / fmaxf((float)cnt2, 1.0f);
        float4 o;
        o.x = bv.x + acc.x * inv; o.y = bv.y + acc.y * inv;
        o.z = bv.z + acc.z * inv; o.w = bv.w + acc.w * inv;
        ((float4*)&out[((size_t)(b * 65 + NSEL + k)) * D_])[tid] = o;
    } else {
        // ---- dominant copies: 1 row per block (selbits only, no spin) ----
        const int i2 = bid - NASG_BLK - NHVY_BLK;  // [0, 1760)
        const int b = i2 / NSEL, r = i2 % NSEL;
        int tok = 0;
        if (r > 0) {
            unsigned long long wsel[9];
            #pragma unroll
            for (int ii = 0; ii < 9; ++ii) wsel[ii] = selbits[b * 9 + ii];
            tok = nth_set_576(wsel, r - 1) + 1;
        }
        const float4* src = (const float4*)&hidden[((size_t)(b * L_ + tok)) * D_];
        ((float4*)&out[((size_t)(b * 65 + r)) * D_])[tid] = src[tid];
    }
}

extern "C" void kernel_launch(void* const* d_in, const int* in_sizes, int n_in,
                              void* d_out, int out_size, void* d_ws, size_t ws_size,
                              hipStream_t stream) {
    const float* attn   = (const float*)d_in[0];
    const float* hidden = (const float*)d_in[1];
    const float* metric = (const float*)d_in[2];
    const float* text   = (const float*)d_in[3];
    float* out = (float*)d_out;

    char* ws = (char*)d_ws;
    size_t off = 0;
    auto alloc = [&](size_t bytes) { void* p = ws + off; off = (off + bytes + 255) & ~(size_t)255; return p; };
    unsigned int* cnt = (unsigned int*)alloc(256);     // [0]=pre, [1..32]=per-batch assign
    float* Sd_part = (float*)alloc((size_t)4 * BL * 4);
    float* cos_arr = (float*)alloc((size_t)BL * 4);
    unsigned long long* selbits = (unsigned long long*)alloc((size_t)B_ * 9 * 8);
    int*   assign_tok = (int*)alloc((size_t)B_ * NMERGE * 4);

    hipMemsetAsync(cnt, 0, 256, stream);
    k_a<<<NA_BLK, 256, 0, stream>>>(attn, metric, text, cnt, Sd_part, cos_arr, selbits);
    k_b<<<NB_BLK, 256, 0, stream>>>(metric, hidden, selbits, cnt, assign_tok, out);
}

// Round 19
// 39.843 us; speedup vs baseline: 3.4181x; 3.4181x over previous
//
#include <hip/hip_runtime.h>

#define B_   32
#define H_   16
#define L_   577
#define D_   1024
#define CK   64
#define LP   576    // L-1 patches = 9*64 exactly
#define DOM  54
#define NSEL 55     // DOM + CLS
#define NR   522    // LP - DOM
#define CTX  10
#define NMERGE 512  // NR - CTX
#define BL   (B_ * LP)

// remain-list position for merge index m: p = m + min(m/51,9) + 1
__device__ __forceinline__ int remain_pos(int m) {
    int k = m / 51; if (k > 9) k = 9;
    return m + k + 1;
}

// position of r-th (0-indexed) set bit of x (must exist)
__device__ __forceinline__ int nth_set_bit64(unsigned long long x, int r) {
    int pos = 0;
    #pragma unroll
    for (int sh = 32; sh >= 1; sh >>= 1) {
        int c = __popcll(x & ((1ull << sh) - 1));
        if (r >= c) { r -= c; x >>= sh; pos += sh; }
    }
    return pos;
}
// r-th zero position over 576-bit mask (9 u64 words)
__device__ int nth_zero_576(const unsigned long long* w, int r) {
    #pragma unroll
    for (int i = 0; i < 9; ++i) {
        int c = 64 - __popcll(w[i]);
        if (r < c) return i * 64 + nth_set_bit64(~w[i], r);
        r -= c;
    }
    return 0; // unreachable
}
// r-th set position over 576-bit mask
__device__ int nth_set_576(const unsigned long long* w, int r) {
    #pragma unroll
    for (int i = 0; i < 9; ++i) {
        int c = __popcll(w[i]);
        if (r < c) return i * 64 + nth_set_bit64(w[i], r);
        r -= c;
    }
    return 0; // unreachable
}

// K0 (COMPACT): 72 Sd blocks (float4 over j) + 1152 cos blocks
// (16-lane groups, float4/lane, 4 rows/wave, one batch per block).
__global__ __launch_bounds__(256) void k_pre(
    const float* __restrict__ attn, const float* __restrict__ metric,
    const float* __restrict__ text, float* __restrict__ Sd_part,
    float* __restrict__ cos_arr)
{
    const int bid = blockIdx.x, tid = threadIdx.x;
    if (bid < 72) {
        // Sd partials: i = (q4, b, j4); thread sums 4 heads over 4 js (float4)
        int i = bid * 256 + tid;                  // [0, BL) = [0, 4*4608)
        int q4 = i / 4608, r = i - q4 * 4608;     // 4608 = B_ * 144
        int b = r / 144, j4 = r - b * 144;
        const size_t LL = (size_t)L_ * L_;
        size_t base = ((size_t)b * H_ + 4 * q4) * LL + 1 + 4 * j4;
        float4 s0 = *(const float4*)&attn[base];
        float4 s1 = *(const float4*)&attn[base + LL];
        float4 s2 = *(const float4*)&attn[base + 2 * LL];
        float4 s3 = *(const float4*)&attn[base + 3 * LL];
        float4 s;
        s.x = (s0.x + s1.x) + (s2.x + s3.x);
        s.y = (s0.y + s1.y) + (s2.y + s3.y);
        s.z = (s0.z + s1.z) + (s2.z + s3.z);
        s.w = (s0.w + s1.w) + (s2.w + s3.w);
        *(float4*)&Sd_part[q4 * BL + b * LP + 4 * j4] = s;
    } else {
        // cos: block serves one batch, 16 rows (4 waves x 4 rows)
        const int cb = bid - 72;                  // [0, 1152)
        const int b = cb / 36, row0 = (cb % 36) * 16;
        const int wv = tid >> 6, lane = tid & 63;
        const int g = lane >> 4, q = lane & 15;
        __shared__ float tsh[CK];
        __shared__ float invtn_sh;

        if (tid < CK) {
            float t = text[b * CK + tid];
            tsh[tid] = t;
            float s2 = t * t;
            for (int o = 32; o; o >>= 1) s2 += __shfl_xor(s2, o);
            if (tid == 0) invtn_sh = 1.f / (sqrtf(s2) + 1e-12f);
        }
        __syncthreads();

        const int j = row0 + wv * 4 + g;          // [0, 576)
        float4 mv = *(const float4*)&metric[((size_t)(b * L_ + 1 + j)) * CK + 4 * q];
        float4 tv = *(const float4*)&tsh[4 * q];
        float d  = mv.x * tv.x + mv.y * tv.y + mv.z * tv.z + mv.w * tv.w;
        float ss = mv.x * mv.x + mv.y * mv.y + mv.z * mv.z + mv.w * mv.w;
        #pragma unroll
        for (int o = 1; o < 16; o <<= 1) {        // stays within 16-lane group
            d += __shfl_xor(d, o); ss += __shfl_xor(ss, o);
        }
        if (q == 0)
            cos_arr[b * LP + j] = d / (sqrtf(ss) + 1e-12f) * invtn_sh;
    }
}

// K1: per-(batch, slice) z-score + rank -> selbits — proven R12/R14/R16
__global__ __launch_bounds__(256) void k_rank(
    const float* __restrict__ Sd_part, const float* __restrict__ cos_arr,
    unsigned long long* __restrict__ selbits)
{
    const int b = blockIdx.x / 9, slice = blockIdx.x % 9;
    const int tid = threadIdx.x, wv = tid >> 6, lane = tid & 63;

    __shared__ float sdv[LP];
    __shared__ float csv[LP];
    __shared__ float red[8];
    __shared__ int   prank[256];

    float sumS = 0.f, sumC = 0.f;
    for (int j = tid; j < LP; j += 256) {
        const int idx = b * LP + j;
        float Sd = (Sd_part[idx] + Sd_part[BL + idx]) +
                   (Sd_part[2 * BL + idx] + Sd_part[3 * BL + idx]);
        float cs = cos_arr[idx];
        sdv[j] = Sd; csv[j] = cs;
        sumS += Sd; sumC += cs;
    }
    {
        float a = sumS, c2 = sumC;
        for (int o = 32; o; o >>= 1) { a += __shfl_xor(a, o); c2 += __shfl_xor(c2, o); }
        if (lane == 0) { red[wv] = a; red[4 + wv] = c2; }
    }
    __syncthreads();
    const float mS = ((red[0] + red[1]) + (red[2] + red[3])) * (1.f / LP);
    const float mC = ((red[4] + red[5]) + (red[6] + red[7])) * (1.f / LP);
    __syncthreads();

    float s2S = 0.f, s2C = 0.f;
    for (int j = tid; j < LP; j += 256) {
        float dS = sdv[j] - mS, dC = csv[j] - mC;
        s2S += dS * dS; s2C += dC * dC;
    }
    {
        float a = s2S, c2 = s2C;
        for (int o = 32; o; o >>= 1) { a += __shfl_xor(a, o); c2 += __shfl_xor(c2, o); }
        if (lane == 0) { red[wv] = a; red[4 + wv] = c2; }
    }
    __syncthreads();
    const float vS = ((red[0] + red[1]) + (red[2] + red[3])) * (1.f / (LP - 1));
    const float vC = ((red[4] + red[5]) + (red[6] + red[7])) * (1.f / (LP - 1));
    const float izS = 0.5f / (sqrtf(vS) + 1e-6f);
    const float izC = 0.5f / (sqrtf(vC) + 1e-6f);
    __syncthreads();

    for (int j = tid; j < LP; j += 256)
        sdv[j] = (sdv[j] - mS) * izS + (csv[j] - mC) * izC;
    __syncthreads();

    {
        const int j = slice * 64 + lane;
        const float my = sdv[j];
        int rk = 0;
        const int k0 = 144 * wv;
        for (int k = k0; k < k0 + 144; ++k) {
            float s = sdv[k];
            rk += (s > my) || (s == my && k < j);   // stable: score desc, idx asc
        }
        prank[tid] = rk;
    }
    __syncthreads();
    if (tid < 64) {
        int tot = (prank[tid] + prank[tid + 64]) + (prank[tid + 128] + prank[tid + 192]);
        unsigned long long bm = __ballot(tot < DOM);
        if (tid == 0) selbits[b * 9 + slice] = bm;
    }
}

// K2: assignment blocks [0,256) + dominant-copy blocks — proven R16
__global__ __launch_bounds__(512) void k_assign(
    const float* __restrict__ metric, const float* __restrict__ hidden,
    const unsigned long long* __restrict__ selbits,
    int* __restrict__ assign_tok, float* __restrict__ out)
{
    const int tid = threadIdx.x;
    if (blockIdx.x < B_ * 8) {
        const int b = blockIdx.x >> 3, sub = blockIdx.x & 7;
        const int wv = tid >> 6, lane = tid & 63;
        __shared__ int   t10[CTX];
        __shared__ float tg[CTX * CK];
        __shared__ float tinv[CTX];

        unsigned long long w[9];
        #pragma unroll
        for (int i = 0; i < 9; ++i) w[i] = selbits[b * 9 + i];

        if (tid < CTX) t10[tid] = nth_zero_576(w, 52 * tid) + 1;
        __syncthreads();
        if (tid < CTX * CK)
            tg[tid] = metric[((size_t)(b * L_ + t10[tid >> 6])) * CK + (tid & 63)];
        {
            int i2 = tid + 512;
            if (i2 < CTX * CK)
                tg[i2] = metric[((size_t)(b * L_ + t10[i2 >> 6])) * CK + (i2 & 63)];
        }
        __syncthreads();
        if (wv < 5) {
            #pragma unroll
            for (int q = 0; q < 2; ++q) {
                int k = 2 * wv + q;
                float t = tg[k * CK + lane];
                float s2 = t * t;
                for (int o = 32; o; o >>= 1) s2 += __shfl_xor(s2, o);
                if (lane == 0) tinv[k] = 1.f / (sqrtf(s2) + 1e-12f);
            }
        }
        __syncthreads();

        const int m = sub * 64 + (tid >> 3);      // token index
        const int e = tid & 7;                     // component-eighth
        const int tok = nth_zero_576(w, remain_pos(m)) + 1;
        const float4* row = (const float4*)&metric[((size_t)(b * L_ + tok)) * CK + 8 * e];
        float4 r0 = row[0], r1 = row[1];

        // merge-row norm dropped: positive scalar, argmax-invariant
        float best = -1e30f; int bk = 0;
        #pragma unroll
        for (int k = 0; k < CTX; ++k) {
            const float4* tp = (const float4*)&tg[k * CK + 8 * e];
            float4 t0 = tp[0], t1 = tp[1];
            float d = (r0.x*t0.x + r0.y*t0.y + r0.z*t0.z + r0.w*t0.w) +
                      (r1.x*t1.x + r1.y*t1.y + r1.z*t1.z + r1.w*t1.w);
            d += __shfl_xor(d, 1); d += __shfl_xor(d, 2); d += __shfl_xor(d, 4);
            d *= tinv[k];
            if (d > best) { best = d; bk = k; }   // strict >: first max (jnp.argmax)
        }
        if (e == 0) assign_tok[b * NMERGE + m] = (tok << 4) | bk;
    } else {
        const int i2 = (blockIdx.x - B_ * 8) * 2 + (tid >> 8);  // row idx [0,1760)
        const int t256 = tid & 255;
        const int b = i2 / NSEL, r = i2 % NSEL;
        int tok = 0;
        if (r > 0) {
            unsigned long long wsel[9];
            #pragma unroll
            for (int ii = 0; ii < 9; ++ii) wsel[ii] = selbits[b * 9 + ii];
            tok = nth_set_576(wsel, r - 1) + 1;
        }
        const float4* src = (const float4*)&hidden[((size_t)(b * L_ + tok)) * D_];
        ((float4*)&out[((size_t)(b * 65 + r)) * D_])[t256] = src[t256];
    }
}

// K3: heavy (contextual) blocks only — proven R12/R14/R16 body
__global__ __launch_bounds__(256) void k_out(
    const float* __restrict__ hidden,
    const unsigned long long* __restrict__ selbits,
    const int* __restrict__ assign_tok, float* __restrict__ out)
{
    const int blk = blockIdx.x;          // [0, B_*CTX)
    const int tid = threadIdx.x;
    const int b = blk / CTX, k = blk % CTX;
    const int w = tid >> 6, lane = tid & 63;
    __shared__ int at[NMERGE];
    __shared__ int toks[NMERGE];
    __shared__ unsigned long long cmask[2][4];

    at[tid]       = assign_tok[b * NMERGE + tid];
    at[tid + 256] = assign_tok[b * NMERGE + tid + 256];
    __syncthreads();
    int a0 = at[tid], a1 = at[tid + 256];
    bool m0 = (a0 & 15) == k, m1 = (a1 & 15) == k;
    unsigned long long bl0 = __ballot(m0), bl1 = __ballot(m1);
    if (lane == 0) { cmask[0][w] = bl0; cmask[1][w] = bl1; }
    __syncthreads();
    int sum0 = 0, pre0 = 0, pre1 = 0;
    #pragma unroll
    for (int ww = 0; ww < 4; ++ww) {
        int p0 = __popcll(cmask[0][ww]);
        sum0 += p0;
        if (ww < w) { pre0 += p0; pre1 += __popcll(cmask[1][ww]); }
    }
    int sum1 = 0;
    #pragma unroll
    for (int ww = 0; ww < 4; ++ww) sum1 += __popcll(cmask[1][ww]);
    unsigned long long lt = (1ull << lane) - 1ull;
    if (m0) toks[pre0 + __popcll(bl0 & lt)] = a0 >> 4;
    if (m1) toks[sum0 + pre1 + __popcll(bl1 & lt)] = a1 >> 4;
    const int cnt = sum0 + sum1;
    __syncthreads();

    const float4* hb = (const float4*)&hidden[((size_t)b * L_) * D_];
    float4 a_0 = make_float4(0,0,0,0), a_1 = a_0, a_2 = a_0, a_3 = a_0;
    float4 a_4 = a_0, a_5 = a_0, a_6 = a_0, a_7 = a_0;
    int i = 0;
    for (; i + 8 <= cnt; i += 8) {
        float4 v0 = hb[(size_t)toks[i+0] * 256 + tid];
        float4 v1 = hb[(size_t)toks[i+1] * 256 + tid];
        float4 v2 = hb[(size_t)toks[i+2] * 256 + tid];
        float4 v3 = hb[(size_t)toks[i+3] * 256 + tid];
        float4 v4 = hb[(size_t)toks[i+4] * 256 + tid];
        float4 v5 = hb[(size_t)toks[i+5] * 256 + tid];
        float4 v6 = hb[(size_t)toks[i+6] * 256 + tid];
        float4 v7 = hb[(size_t)toks[i+7] * 256 + tid];
        a_0.x += v0.x; a_0.y += v0.y; a_0.z += v0.z; a_0.w += v0.w;
        a_1.x += v1.x; a_1.y += v1.y; a_1.z += v1.z; a_1.w += v1.w;
        a_2.x += v2.x; a_2.y += v2.y; a_2.z += v2.z; a_2.w += v2.w;
        a_3.x += v3.x; a_3.y += v3.y; a_3.z += v3.z; a_3.w += v3.w;
        a_4.x += v4.x; a_4.y += v4.y; a_4.z += v4.z; a_4.w += v4.w;
        a_5.x += v5.x; a_5.y += v5.y; a_5.z += v5.z; a_5.w += v5.w;
        a_6.x += v6.x; a_6.y += v6.y; a_6.z += v6.z; a_6.w += v6.w;
        a_7.x += v7.x; a_7.y += v7.y; a_7.z += v7.z; a_7.w += v7.w;
    }
    for (; i < cnt; ++i) {
        float4 v = hb[(size_t)toks[i] * 256 + tid];
        a_0.x += v.x; a_0.y += v.y; a_0.z += v.z; a_0.w += v.w;
    }
    float4 acc;
    acc.x = ((a_0.x + a_1.x) + (a_2.x + a_3.x)) + ((a_4.x + a_5.x) + (a_6.x + a_7.x));
    acc.y = ((a_0.y + a_1.y) + (a_2.y + a_3.y)) + ((a_4.y + a_5.y) + (a_6.y + a_7.y));
    acc.z = ((a_0.z + a_1.z) + (a_2.z + a_3.z)) + ((a_4.z + a_5.z) + (a_6.z + a_7.z));
    acc.w = ((a_0.w + a_1.w) + (a_2.w + a_3.w)) + ((a_4.w + a_5.w) + (a_6.w + a_7.w));

    unsigned long long wsel[9];
    #pragma unroll
    for (int ii = 0; ii < 9; ++ii) wsel[ii] = selbits[b * 9 + ii];
    const int tgt_tok = nth_zero_576(wsel, 52 * k) + 1;
    float4 bv = hb[(size_t)tgt_tok * 256 + tid];
    float inv = 1.0f / fmaxf((float)cnt, 1.0f);
    float4 o;
    o.x = bv.x + acc.x * inv; o.y = bv.y + acc.y * inv;
    o.z = bv.z + acc.z * inv; o.w = bv.w + acc.w * inv;
    ((float4*)&out[((size_t)(b * 65 + NSEL + k)) * D_])[tid] = o;
}

extern "C" void kernel_launch(void* const* d_in, const int* in_sizes, int n_in,
                              void* d_out, int out_size, void* d_ws, size_t ws_size,
                              hipStream_t stream) {
    const float* attn   = (const float*)d_in[0];
    const float* hidden = (const float*)d_in[1];
    const float* metric = (const float*)d_in[2];
    const float* text   = (const float*)d_in[3];
    float* out = (float*)d_out;

    char* ws = (char*)d_ws;
    size_t off = 0;
    auto alloc = [&](size_t bytes) { void* p = ws + off; off = (off + bytes + 255) & ~(size_t)255; return p; };
    float* Sd_part = (float*)alloc((size_t)4 * BL * 4);
    float* cos_arr = (float*)alloc((size_t)BL * 4);
    unsigned long long* selbits = (unsigned long long*)alloc((size_t)B_ * 9 * 8);
    int*   assign_tok = (int*)alloc((size_t)B_ * NMERGE * 4);

    k_pre   <<<72 + 1152, 256, 0, stream>>>(attn, metric, text, Sd_part, cos_arr);
    k_rank  <<<B_ * 9, 256, 0, stream>>>(Sd_part, cos_arr, selbits);
    k_assign<<<B_ * 8 + (B_ * NSEL) / 2, 512, 0, stream>>>(metric, hidden, selbits,
                                                           assign_tok, out);
    k_out   <<<B_ * CTX, 256, 0, stream>>>(hidden, selbits, assign_tok, out);
}